// Round 1
// baseline (168.764 us; speedup 1.0000x reference)
//
#include <hip/hip_runtime.h>

#define NUM_FEATURES 256
#define NUM_SAMPLES  262144
#define BATCH        1024

// One wave (64 lanes) per batch entry. Block b "owns" target y = targets[b]
// iff b is the FIRST occurrence of y in the batch. The owner applies every
// update with that target in batch order (sequential-chain semantics for
// duplicates), then writes the final normalized row once.
// Each lane holds float4 => 64*4 = 256 features, fully coalesced 16B/lane.
__global__ __launch_bounds__(64) void memory_bank_update(
    const float* __restrict__ inputs,    // [BATCH, F]
    const int*   __restrict__ targets,   // [BATCH]
    const float* __restrict__ features,  // [NUM_SAMPLES, F] (original table)
    float*       __restrict__ out)       // [NUM_SAMPLES, F] (already copied)
{
    const int b = blockIdx.x;
    const int y = targets[b];

    // First-occurrence ownership check (uniform scalar loop, L2/sK-cached).
    for (int j = 0; j < b; ++j) {
        if (targets[j] == y) return;  // earlier block owns this chain
    }

    const int lane = threadIdx.x;  // 0..63
    float4 v = reinterpret_cast<const float4*>(
                   features + (size_t)y * NUM_FEATURES)[lane];

    const float m  = 0.1f;
    const float om = 1.0f - m;  // matches jnp: 1.0 - float32(0.1)

    for (int i = b; i < BATCH; ++i) {
        if (targets[i] != y) continue;
        float4 x = reinterpret_cast<const float4*>(
                       inputs + (size_t)i * NUM_FEATURES)[lane];
        v.x = m * v.x + om * x.x;
        v.y = m * v.y + om * x.y;
        v.z = m * v.z + om * x.z;
        v.w = m * v.w + om * x.w;

        // ||v||^2 across the wave: per-lane partial, then 64-lane butterfly.
        float s = v.x * v.x + v.y * v.y + v.z * v.z + v.w * v.w;
        #pragma unroll
        for (int off = 32; off > 0; off >>= 1)
            s += __shfl_xor(s, off);

        const float inv = 1.0f / fmaxf(sqrtf(s), 1e-12f);
        v.x *= inv; v.y *= inv; v.z *= inv; v.w *= inv;
    }

    reinterpret_cast<float4*>(out + (size_t)y * NUM_FEATURES)[lane] = v;
}

extern "C" void kernel_launch(void* const* d_in, const int* in_sizes, int n_in,
                              void* d_out, int out_size, void* d_ws, size_t ws_size,
                              hipStream_t stream) {
    const float* inputs   = (const float*)d_in[0];
    const int*   targets  = (const int*)d_in[1];
    const float* features = (const float*)d_in[2];
    float*       out      = (float*)d_out;

    // Bulk table copy: 256 MiB, the HBM-roofline-dominant part (~85 us).
    hipMemcpyAsync(out, features,
                   (size_t)NUM_SAMPLES * NUM_FEATURES * sizeof(float),
                   hipMemcpyDeviceToDevice, stream);

    // Then overwrite the 1024 touched rows with the chained updates.
    memory_bank_update<<<BATCH, 64, 0, stream>>>(inputs, targets, features, out);
}

// Round 3
// 167.188 us; speedup vs baseline: 1.0094x; 1.0094x over previous
//
#include <hip/hip_runtime.h>

#define NUM_FEATURES 256
#define NUM_SAMPLES  262144
#define BATCH        1024

typedef float f4 __attribute__((ext_vector_type(4)));

// Grid-stride float4 copy: 256 MiB read + 256 MiB write. 16 B/lane fully
// coalesced; nontemporal hints keep the one-shot stream from thrashing L2.
__global__ __launch_bounds__(256) void table_copy(
    const f4* __restrict__ src, f4* __restrict__ dst, long n4)
{
    long i = (long)blockIdx.x * blockDim.x + threadIdx.x;
    const long stride = (long)gridDim.x * blockDim.x;
    for (; i < n4; i += stride) {
        f4 v = __builtin_nontemporal_load(&src[i]);
        __builtin_nontemporal_store(v, &dst[i]);
    }
}

// One wave (64 lanes) per batch entry. Block b "owns" target y = targets[b]
// iff b is the FIRST occurrence of y in the batch. The owner applies every
// update with that target in batch order (sequential-chain semantics for
// duplicates), then writes the final normalized row once.
// Each lane holds float4 => 64*4 = 256 features, fully coalesced 16B/lane.
__global__ __launch_bounds__(64) void memory_bank_update(
    const float* __restrict__ inputs,    // [BATCH, F]
    const int*   __restrict__ targets,   // [BATCH]
    const float* __restrict__ features,  // [NUM_SAMPLES, F] (original table)
    float*       __restrict__ out)       // [NUM_SAMPLES, F] (already copied)
{
    const int b = blockIdx.x;
    const int y = targets[b];

    // First-occurrence ownership check (uniform scalar loop, L2-cached).
    for (int j = 0; j < b; ++j) {
        if (targets[j] == y) return;  // earlier block owns this chain
    }

    const int lane = threadIdx.x;  // 0..63
    float4 v = reinterpret_cast<const float4*>(
                   features + (size_t)y * NUM_FEATURES)[lane];

    const float m  = 0.1f;
    const float om = 1.0f - m;

    for (int i = b; i < BATCH; ++i) {
        if (targets[i] != y) continue;
        float4 x = reinterpret_cast<const float4*>(
                       inputs + (size_t)i * NUM_FEATURES)[lane];
        v.x = m * v.x + om * x.x;
        v.y = m * v.y + om * x.y;
        v.z = m * v.z + om * x.z;
        v.w = m * v.w + om * x.w;

        // ||v||^2 across the wave: per-lane partial, then 64-lane butterfly.
        float s = v.x * v.x + v.y * v.y + v.z * v.z + v.w * v.w;
        #pragma unroll
        for (int off = 32; off > 0; off >>= 1)
            s += __shfl_xor(s, off);

        const float inv = 1.0f / fmaxf(sqrtf(s), 1e-12f);
        v.x *= inv; v.y *= inv; v.z *= inv; v.w *= inv;
    }

    reinterpret_cast<float4*>(out + (size_t)y * NUM_FEATURES)[lane] = v;
}

extern "C" void kernel_launch(void* const* d_in, const int* in_sizes, int n_in,
                              void* d_out, int out_size, void* d_ws, size_t ws_size,
                              hipStream_t stream) {
    const float* inputs   = (const float*)d_in[0];
    const int*   targets  = (const int*)d_in[1];
    const float* features = (const float*)d_in[2];
    float*       out      = (float*)d_out;

    const long n4 = (long)NUM_SAMPLES * NUM_FEATURES / 4;  // 16.7M float4
    table_copy<<<2048, 256, 0, stream>>>(
        reinterpret_cast<const f4*>(features),
        reinterpret_cast<f4*>(out), n4);

    // Then overwrite the 1024 touched rows with the chained updates.
    memory_bank_update<<<BATCH, 64, 0, stream>>>(inputs, targets, features, out);
}

// Round 4
// 103.509 us; speedup vs baseline: 1.6304x; 1.6152x over previous
//
#include <hip/hip_runtime.h>

#define NUM_FEATURES 256
#define NUM_SAMPLES  262144
#define BATCH        1024

typedef float f4 __attribute__((ext_vector_type(4)));

// Grid-stride float4 copy: 256 MiB read + 256 MiB write, 16 B/lane coalesced.
__global__ __launch_bounds__(256) void table_copy(
    const f4* __restrict__ src, f4* __restrict__ dst, long n4)
{
    long i = (long)blockIdx.x * blockDim.x + threadIdx.x;
    const long stride = (long)gridDim.x * blockDim.x;
    for (; i < n4; i += stride) {
        f4 v = __builtin_nontemporal_load(&src[i]);
        __builtin_nontemporal_store(v, &dst[i]);
    }
}

// One wave per batch entry. Block b owns target y = targets[b] iff b is the
// FIRST occurrence of y. Targets are staged in LDS so ownership check and
// chain scan are ballot-based (<=16 iterations), not serial global loads.
__global__ __launch_bounds__(64) void memory_bank_update(
    const float* __restrict__ inputs,    // [BATCH, F]
    const int*   __restrict__ targets,   // [BATCH]
    const float* __restrict__ features,  // [NUM_SAMPLES, F] (original table)
    float*       __restrict__ out)       // [NUM_SAMPLES, F] (already copied)
{
    __shared__ int t[BATCH];
    const int lane = threadIdx.x;  // 0..63
    const int b = blockIdx.x;

    // Stage all 1024 targets: 4 rounds of coalesced int4 loads.
    const int4* tg4 = reinterpret_cast<const int4*>(targets);
    int4* t4 = reinterpret_cast<int4*>(t);
    #pragma unroll
    for (int k = 0; k < BATCH / 4 / 64; ++k)
        t4[k * 64 + lane] = tg4[k * 64 + lane];
    __syncthreads();

    const int y = t[b];

    // Ownership: does y appear in t[0..b-1]?  Ballot over 64-wide chunks.
    for (int base = 0; base < b; base += 64) {
        const int j = base + lane;
        if (__any(j < b && t[j] == y)) return;  // earlier occurrence owns it
    }

    f4 v = reinterpret_cast<const f4*>(features + (size_t)y * NUM_FEATURES)[lane];

    const float m  = 0.1f;
    const float om = 1.0f - m;

    // Chain scan: find all i in [b, BATCH) with t[i]==y, in order, via
    // ballot + ffs. Mask is wave-uniform -> non-divergent processing loop.
    for (int base = b & ~63; base < BATCH; base += 64) {
        const int i = base + lane;
        unsigned long long mask = __ballot(i >= b && t[i] == y);
        while (mask) {
            const int i0 = base + (__ffsll((long long)mask) - 1);
            mask &= mask - 1;

            f4 x = reinterpret_cast<const f4*>(
                       inputs + (size_t)i0 * NUM_FEATURES)[lane];
            v.x = m * v.x + om * x.x;
            v.y = m * v.y + om * x.y;
            v.z = m * v.z + om * x.z;
            v.w = m * v.w + om * x.w;

            float s = v.x * v.x + v.y * v.y + v.z * v.z + v.w * v.w;
            #pragma unroll
            for (int off = 32; off > 0; off >>= 1)
                s += __shfl_xor(s, off);

            const float inv = 1.0f / fmaxf(sqrtf(s), 1e-12f);
            v.x *= inv; v.y *= inv; v.z *= inv; v.w *= inv;
        }
    }

    reinterpret_cast<f4*>(out + (size_t)y * NUM_FEATURES)[lane] = v;
}

extern "C" void kernel_launch(void* const* d_in, const int* in_sizes, int n_in,
                              void* d_out, int out_size, void* d_ws, size_t ws_size,
                              hipStream_t stream) {
    const float* inputs   = (const float*)d_in[0];
    const int*   targets  = (const int*)d_in[1];
    const float* features = (const float*)d_in[2];
    float*       out      = (float*)d_out;

    const long n4 = (long)NUM_SAMPLES * NUM_FEATURES / 4;  // 16.7M float4
    table_copy<<<2048, 256, 0, stream>>>(
        reinterpret_cast<const f4*>(features),
        reinterpret_cast<f4*>(out), n4);

    // Then overwrite the 1024 touched rows with the chained updates.
    memory_bank_update<<<BATCH, 64, 0, stream>>>(inputs, targets, features, out);
}